// Round 1
// baseline (294.320 us; speedup 1.0000x reference)
//
#include <hip/hip_runtime.h>

// Problem constants
constexpr int Bb   = 2;
constexpr int Nn   = 2048;
constexpr int Hh   = 8;
constexpr int Dd   = 64;
constexpr int Mm   = Bb * Nn;      // 4096 rows
constexpr int TQKV = 1536;         // 3 * H * D
constexpr int INNER = Hh * Dd;     // 512
constexpr int CH   = 64;           // chunk length
constexpr int NCH  = Nn / CH;      // 32 chunks per (b,h)
constexpr int CSZ  = Dd * Dd + Dd; // 4160 floats per chunk record (S + kc)
constexpr float EPSF = 1e-7f;

// ---------------------------------------------------------------------------
// Generic NT GEMM: C[M,N] = A[M,K] * B[N,K]^T (+bias). Both operands K-inner.
// BT x BT tile, 256 threads, (BT/16)^2 per-thread tile, K-step 16.
// ---------------------------------------------------------------------------
template <int BT>
__global__ __launch_bounds__(256) void gemm_nt(
    const float* __restrict__ A, const float* __restrict__ Bm,
    const float* __restrict__ bias, float* __restrict__ C,
    int Mdim, int Ndim, int Kdim) {
  constexpr int TT = BT / 16;
  constexpr int KT = 16;
  __shared__ float As[KT][BT];
  __shared__ float Bs[KT][BT];
  const int tid = threadIdx.x;
  const int tx = tid & 15, ty = tid >> 4;
  const int bn = blockIdx.x * BT, bm = blockIdx.y * BT;

  float acc[TT][TT];
#pragma unroll
  for (int i = 0; i < TT; ++i)
#pragma unroll
    for (int j = 0; j < TT; ++j) acc[i][j] = 0.f;

  for (int k0 = 0; k0 < Kdim; k0 += KT) {
#pragma unroll
    for (int i = tid; i < BT * KT / 4; i += 256) {
      int row = i >> 2;        // 4 float4 per row (KT=16)
      int c4 = i & 3;
      float4 fa = *(const float4*)(A + (size_t)(bm + row) * Kdim + k0 + c4 * 4);
      As[c4 * 4 + 0][row] = fa.x; As[c4 * 4 + 1][row] = fa.y;
      As[c4 * 4 + 2][row] = fa.z; As[c4 * 4 + 3][row] = fa.w;
      float4 fb = *(const float4*)(Bm + (size_t)(bn + row) * Kdim + k0 + c4 * 4);
      Bs[c4 * 4 + 0][row] = fb.x; Bs[c4 * 4 + 1][row] = fb.y;
      Bs[c4 * 4 + 2][row] = fb.z; Bs[c4 * 4 + 3][row] = fb.w;
    }
    __syncthreads();
#pragma unroll
    for (int kk = 0; kk < KT; ++kk) {
      float av[TT], bv[TT];
#pragma unroll
      for (int i = 0; i < TT; i += 4)
        *(float4*)&av[i] = *(const float4*)&As[kk][ty * TT + i];
#pragma unroll
      for (int j = 0; j < TT; j += 4)
        *(float4*)&bv[j] = *(const float4*)&Bs[kk][tx * TT + j];
#pragma unroll
      for (int i = 0; i < TT; ++i)
#pragma unroll
        for (int j = 0; j < TT; ++j) acc[i][j] += av[i] * bv[j];
    }
    __syncthreads();
  }

#pragma unroll
  for (int i = 0; i < TT; ++i) {
    size_t row = bm + ty * TT + i;
#pragma unroll
    for (int j = 0; j < TT; j += 4) {
      int col = bn + tx * TT + j;
      float4 r;
      r.x = acc[i][j + 0]; r.y = acc[i][j + 1];
      r.z = acc[i][j + 2]; r.w = acc[i][j + 3];
      if (bias) {
        r.x += bias[col + 0]; r.y += bias[col + 1];
        r.z += bias[col + 2]; r.w += bias[col + 3];
      }
      *(float4*)(C + row * (size_t)Ndim + col) = r;
    }
  }
}

// ---------------------------------------------------------------------------
// Per-head LayerNorm over D=64 on the k and v segments of qkv, in place.
// One wave per (b,n,h) row; lane = d.
// ---------------------------------------------------------------------------
__global__ __launch_bounds__(256) void ln_kv(
    float* __restrict__ qkv,
    const float* __restrict__ lnk_w, const float* __restrict__ lnk_b,
    const float* __restrict__ lnv_w, const float* __restrict__ lnv_b) {
  int wave = (blockIdx.x * 256 + threadIdx.x) >> 6;
  int lane = threadIdx.x & 63;
  const int total = Bb * Nn * Hh;
  bool isv = wave >= total;
  int r = isv ? wave - total : wave;   // (b*N+n)*H + h
  int bn = r / Hh, h = r % Hh;
  float* p = qkv + (size_t)bn * TQKV + (isv ? 2 * INNER : INNER) + h * Dd + lane;
  float val = *p;
  float s = val, s2 = val * val;
#pragma unroll
  for (int off = 32; off; off >>= 1) {
    s += __shfl_xor(s, off, 64);
    s2 += __shfl_xor(s2, off, 64);
  }
  float mean = s * (1.f / 64.f);
  float var = s2 * (1.f / 64.f) - mean * mean;
  float inv = 1.0f / sqrtf(var + EPSF);
  const float* w = isv ? lnv_w : lnk_w;
  const float* b = isv ? lnv_b : lnk_b;
  *p = (val - mean) * inv * w[h * Dd + lane] + b[h * Dd + lane];
}

// ---------------------------------------------------------------------------
// Pass 1: per-chunk S_c = K_c^T V_c [64x64] and kc_c = colsum(K_c) [64].
// Block per (b,h,c). cbuf record: [S(4096) | kc(64)].
// ---------------------------------------------------------------------------
__global__ __launch_bounds__(256) void chunk_sums(
    const float* __restrict__ qkv, float* __restrict__ cbuf) {
  int blk = blockIdx.x;
  int c = blk % NCH;
  int bh = blk / NCH;
  int h = bh % Hh, b = bh / Hh;
  __shared__ float Ks[CH][68];
  __shared__ float Vs[CH][68];
  int tid = threadIdx.x;
  const float* base = qkv + (size_t)(b * Nn + c * CH) * TQKV + h * Dd;
  for (int i = tid; i < CH * 16; i += 256) {
    int row = i >> 4, c4 = i & 15;
    *(float4*)&Ks[row][c4 * 4] =
        *(const float4*)(base + (size_t)row * TQKV + INNER + c4 * 4);
    *(float4*)&Vs[row][c4 * 4] =
        *(const float4*)(base + (size_t)row * TQKV + 2 * INNER + c4 * 4);
  }
  __syncthreads();
  int d0 = (tid >> 4) * 4, e0 = (tid & 15) * 4;
  float acc[4][4] = {};
  float kc[4] = {0.f, 0.f, 0.f, 0.f};
  for (int n = 0; n < CH; ++n) {
    float4 kv = *(const float4*)&Ks[n][d0];
    float4 vv = *(const float4*)&Vs[n][e0];
    float ka[4] = {kv.x, kv.y, kv.z, kv.w};
    float va[4] = {vv.x, vv.y, vv.z, vv.w};
#pragma unroll
    for (int i = 0; i < 4; ++i)
#pragma unroll
      for (int j = 0; j < 4; ++j) acc[i][j] += ka[i] * va[j];
    if (e0 == 0) {
#pragma unroll
      for (int i = 0; i < 4; ++i) kc[i] += ka[i];
    }
  }
  float* out = cbuf + (size_t)blk * CSZ;
#pragma unroll
  for (int i = 0; i < 4; ++i) {
    float4 r;
    r.x = acc[i][0]; r.y = acc[i][1]; r.z = acc[i][2]; r.w = acc[i][3];
    *(float4*)(out + (size_t)(d0 + i) * Dd + e0) = r;
  }
  if (e0 == 0) {
#pragma unroll
    for (int i = 0; i < 4; ++i) out[Dd * Dd + d0 + i] = kc[i];
  }
}

// ---------------------------------------------------------------------------
// Pass 2: exclusive prefix over chunks, per (b,h). Block per (b,h).
// ---------------------------------------------------------------------------
__global__ __launch_bounds__(256) void chunk_prefix(float* __restrict__ cbuf) {
  int bh = blockIdx.x;
  float* base = cbuf + (size_t)bh * NCH * CSZ;
  for (int i = threadIdx.x; i < CSZ; i += 256) {
    float carry = 0.f;
    for (int c = 0; c < NCH; ++c) {
      float* p = base + (size_t)c * CSZ + i;
      float t = *p;
      *p = carry;
      carry += t;
    }
  }
}

// ---------------------------------------------------------------------------
// Pass 3: per chunk attention.
// Out[n,e] = (Q·S_pref + (QK^T ∘ causal)·V)[n,e] / (N * denom[n])
// denom[n] = q_n·kc_pref + rowsum((QK^T ∘ causal))[n] + EPS * sum_d q_n[d]
// ---------------------------------------------------------------------------
__global__ __launch_bounds__(256) void chunk_attn(
    const float* __restrict__ qkv, const float* __restrict__ cbuf,
    float* __restrict__ attn) {
  int blk = blockIdx.x;
  int c = blk % NCH;
  int bh = blk / NCH;
  int h = bh % Hh, b = bh / Hh;
  __shared__ float Qs[64][68];   // [d][n] transposed
  __shared__ float Ks[64][68];   // [d][m] transposed
  __shared__ float Vs[64][68];   // [m][e]
  __shared__ float Ps[64][68];   // [m][n] masked P, transposed
  __shared__ float Ss[64][68];   // [d][e] S_prefix
  __shared__ float kcs[64];
  __shared__ float rs[64][17];
  __shared__ float denomS[64];

  int tid = threadIdx.x;
  int tx = tid & 15, ty = tid >> 4;
  const float* base = qkv + (size_t)(b * Nn + c * CH) * TQKV + h * Dd;
  for (int i = tid; i < CH * 16; i += 256) {
    int row = i >> 4, c4 = i & 15;
    float4 fq = *(const float4*)(base + (size_t)row * TQKV + c4 * 4);
    Qs[c4 * 4 + 0][row] = fq.x; Qs[c4 * 4 + 1][row] = fq.y;
    Qs[c4 * 4 + 2][row] = fq.z; Qs[c4 * 4 + 3][row] = fq.w;
    float4 fk = *(const float4*)(base + (size_t)row * TQKV + INNER + c4 * 4);
    Ks[c4 * 4 + 0][row] = fk.x; Ks[c4 * 4 + 1][row] = fk.y;
    Ks[c4 * 4 + 2][row] = fk.z; Ks[c4 * 4 + 3][row] = fk.w;
    float4 fv = *(const float4*)(base + (size_t)row * TQKV + 2 * INNER + c4 * 4);
    *(float4*)&Vs[row][c4 * 4] = fv;
  }
  const float* sp = cbuf + (size_t)blk * CSZ;
  for (int i = tid; i < 1024; i += 256) {
    int row = i >> 4, c4 = i & 15;
    *(float4*)&Ss[row][c4 * 4] = *(const float4*)(sp + (size_t)i * 4);
    (void)row; (void)c4;
  }
  if (tid < 16) {
    float4 f = *(const float4*)(sp + Dd * Dd + tid * 4);
    kcs[tid * 4 + 0] = f.x; kcs[tid * 4 + 1] = f.y;
    kcs[tid * 4 + 2] = f.z; kcs[tid * 4 + 3] = f.w;
  }
  __syncthreads();

  // Phase B: P = Q K^T (this chunk), causal mask, rowsum
  float accP[4][4] = {};
  for (int kk = 0; kk < 64; ++kk) {
    float4 qa = *(const float4*)&Qs[kk][ty * 4];
    float4 kb = *(const float4*)&Ks[kk][tx * 4];
    float qv[4] = {qa.x, qa.y, qa.z, qa.w};
    float kv[4] = {kb.x, kb.y, kb.z, kb.w};
#pragma unroll
    for (int i = 0; i < 4; ++i)
#pragma unroll
      for (int j = 0; j < 4; ++j) accP[i][j] += qv[i] * kv[j];
  }
#pragma unroll
  for (int i = 0; i < 4; ++i) {
    int n = ty * 4 + i;
    float rsum = 0.f;
#pragma unroll
    for (int j = 0; j < 4; ++j) {
      int m = tx * 4 + j;
      float p = (m <= n) ? accP[i][j] : 0.f;
      Ps[m][n] = p;
      rsum += p;
    }
    rs[n][tx] = rsum;
  }
  __syncthreads();

  // Phase C: O = Q * S_prefix; denom pieces
  float accO[4][4] = {};
  for (int d = 0; d < 64; ++d) {
    float4 qa = *(const float4*)&Qs[d][ty * 4];
    float4 sb = *(const float4*)&Ss[d][tx * 4];
    float qv[4] = {qa.x, qa.y, qa.z, qa.w};
    float sv[4] = {sb.x, sb.y, sb.z, sb.w};
#pragma unroll
    for (int i = 0; i < 4; ++i)
#pragma unroll
      for (int j = 0; j < 4; ++j) accO[i][j] += qv[i] * sv[j];
  }
  if (tid < 64) {
    int n = tid;
    float qkc = 0.f, qs = 0.f;
    for (int d = 0; d < 64; ++d) {
      float q = Qs[d][n];
      qkc += q * kcs[d];
      qs += q;
    }
    float rsum = 0.f;
#pragma unroll
    for (int t2 = 0; t2 < 16; ++t2) rsum += rs[n][t2];
    denomS[n] = qkc + rsum + EPSF * qs;
  }
  __syncthreads();

  // Phase D: O += P_masked * V
  for (int m = 0; m < 64; ++m) {
    float4 pa = *(const float4*)&Ps[m][ty * 4];
    float4 vb = *(const float4*)&Vs[m][tx * 4];
    float pv[4] = {pa.x, pa.y, pa.z, pa.w};
    float vv[4] = {vb.x, vb.y, vb.z, vb.w};
#pragma unroll
    for (int i = 0; i < 4; ++i)
#pragma unroll
      for (int j = 0; j < 4; ++j) accO[i][j] += pv[i] * vv[j];
  }

  float* aout = attn + (size_t)(b * Nn + c * CH) * INNER + h * Dd;
#pragma unroll
  for (int i = 0; i < 4; ++i) {
    int n = ty * 4 + i;
    float dinv = 1.0f / denomS[n];
    float scale = dinv * (1.0f / (float)Nn);
    float4 r;
    r.x = accO[i][0] * scale; r.y = accO[i][1] * scale;
    r.z = accO[i][2] * scale; r.w = accO[i][3] * scale;
    *(float4*)(aout + (size_t)n * INNER + tx * 4) = r;
  }
}

// ---------------------------------------------------------------------------
extern "C" void kernel_launch(void* const* d_in, const int* in_sizes, int n_in,
                              void* d_out, int out_size, void* d_ws,
                              size_t ws_size, hipStream_t stream) {
  const float* x     = (const float*)d_in[0];
  const float* w_qkv = (const float*)d_in[1];
  const float* lnk_w = (const float*)d_in[2];
  const float* lnk_b = (const float*)d_in[3];
  const float* lnv_w = (const float*)d_in[4];
  const float* lnv_b = (const float*)d_in[5];
  const float* w_out = (const float*)d_in[6];
  const float* b_out = (const float*)d_in[7];
  float* out = (float*)d_out;

  float* qkv  = (float*)d_ws;                              // 4096*1536 floats
  float* cbuf = qkv + (size_t)Mm * TQKV;                   // 512*4160 floats
  float* attn = cbuf + (size_t)Bb * Hh * NCH * CSZ;        // 4096*512 floats

  // 1. QKV GEMM: [4096,1536] = x[4096,512] * w_qkv[1536,512]^T
  gemm_nt<128><<<dim3(TQKV / 128, Mm / 128), 256, 0, stream>>>(
      x, w_qkv, nullptr, qkv, Mm, TQKV, 512);

  // 2. Per-head LayerNorm on k, v (in place)
  ln_kv<<<(2 * Bb * Nn * Hh * 64) / 256, 256, 0, stream>>>(
      qkv, lnk_w, lnk_b, lnv_w, lnv_b);

  // 3. Per-chunk K^T V and colsum(K)
  chunk_sums<<<Bb * Hh * NCH, 256, 0, stream>>>(qkv, cbuf);

  // 4. Exclusive prefix over chunks
  chunk_prefix<<<Bb * Hh, 256, 0, stream>>>(cbuf);

  // 5. Per-chunk attention -> attn [4096, 512]
  chunk_attn<<<Bb * Hh * NCH, 256, 0, stream>>>(qkv, cbuf, attn);

  // 6. Output GEMM: out[4096,512] = attn * w_out[512,512]^T + b_out
  gemm_nt<64><<<dim3(INNER / 64, Mm / 64), 256, 0, stream>>>(
      attn, w_out, b_out, out, Mm, INNER, 512);
}

// Round 4
// 244.332 us; speedup vs baseline: 1.2046x; 1.2046x over previous
//
#include <hip/hip_runtime.h>

// Problem constants
constexpr int Bb   = 2;
constexpr int Nn   = 2048;
constexpr int Hh   = 8;
constexpr int Dd   = 64;
constexpr int Mm   = Bb * Nn;      // 4096 rows
constexpr int TQKV = 1536;         // 3 * H * D
constexpr int INNER = Hh * Dd;     // 512
constexpr int CH   = 64;           // chunk length
constexpr int NCH  = Nn / CH;      // 32 chunks per (b,h)
constexpr int CSZ  = Dd * Dd + Dd; // 4160 floats per chunk record (S + kc)
constexpr float EPSF = 1e-7f;

typedef _Float16 half8 __attribute__((ext_vector_type(8)));
typedef _Float16 half4 __attribute__((ext_vector_type(4)));
typedef float f32x4 __attribute__((ext_vector_type(4)));

#define AS1(p) ((const __attribute__((address_space(1))) unsigned int*)(p))
#define AS3(p) ((__attribute__((address_space(3))) unsigned int*)(p))

// ---------------------------------------------------------------------------
// fp32 NT GEMM: C[M,N] = A[M,K] * B[N,K]^T (+bias).
// R3 post-mortem: split-f16 (2^-22 residual) amplifies to 0.875 absmax via the
// denominator spikes — q/k MUST be fp32-class. This kernel is numerically
// identical to the R1-passing version (same sequential-k accumulation).
// BT=64: 1536 blocks -> ~20 waves/CU (vs R1's 384 blocks / 6 waves/CU).
// ---------------------------------------------------------------------------
template <int BT>
__global__ __launch_bounds__(256) void gemm_nt(
    const float* __restrict__ A, const float* __restrict__ Bm,
    const float* __restrict__ bias, float* __restrict__ C,
    int Mdim, int Ndim, int Kdim) {
  constexpr int TT = BT / 16;
  constexpr int KT = 16;
  __shared__ float As[KT][BT];
  __shared__ float Bs[KT][BT];
  const int tid = threadIdx.x;
  const int tx = tid & 15, ty = tid >> 4;
  const int bn = blockIdx.x * BT, bm = blockIdx.y * BT;

  float acc[TT][TT];
#pragma unroll
  for (int i = 0; i < TT; ++i)
#pragma unroll
    for (int j = 0; j < TT; ++j) acc[i][j] = 0.f;

  for (int k0 = 0; k0 < Kdim; k0 += KT) {
#pragma unroll
    for (int i = tid; i < BT * KT / 4; i += 256) {
      int row = i >> 2;
      int c4 = i & 3;
      float4 fa = *(const float4*)(A + (size_t)(bm + row) * Kdim + k0 + c4 * 4);
      As[c4 * 4 + 0][row] = fa.x; As[c4 * 4 + 1][row] = fa.y;
      As[c4 * 4 + 2][row] = fa.z; As[c4 * 4 + 3][row] = fa.w;
      float4 fb = *(const float4*)(Bm + (size_t)(bn + row) * Kdim + k0 + c4 * 4);
      Bs[c4 * 4 + 0][row] = fb.x; Bs[c4 * 4 + 1][row] = fb.y;
      Bs[c4 * 4 + 2][row] = fb.z; Bs[c4 * 4 + 3][row] = fb.w;
    }
    __syncthreads();
#pragma unroll
    for (int kk = 0; kk < KT; ++kk) {
      float av[TT], bv[TT];
#pragma unroll
      for (int i = 0; i < TT; i += 4)
        *(float4*)&av[i] = *(const float4*)&As[kk][ty * TT + i];
#pragma unroll
      for (int j = 0; j < TT; j += 4)
        *(float4*)&bv[j] = *(const float4*)&Bs[kk][tx * TT + j];
#pragma unroll
      for (int i = 0; i < TT; ++i)
#pragma unroll
        for (int j = 0; j < TT; ++j) acc[i][j] += av[i] * bv[j];
    }
    __syncthreads();
  }

#pragma unroll
  for (int i = 0; i < TT; ++i) {
    size_t row = bm + ty * TT + i;
#pragma unroll
    for (int j = 0; j < TT; j += 4) {
      int col = bn + tx * TT + j;
      float4 r;
      r.x = acc[i][j + 0]; r.y = acc[i][j + 1];
      r.z = acc[i][j + 2]; r.w = acc[i][j + 3];
      if (bias) {
        r.x += bias[col + 0]; r.y += bias[col + 1];
        r.z += bias[col + 2]; r.w += bias[col + 3];
      }
      *(float4*)(C + row * (size_t)Ndim + col) = r;
    }
  }
}

// ---------------------------------------------------------------------------
// Split fp32 -> (hi f16, lo f16 * 2^11). Only used for w_out / attn (GEMM2),
// whose 2^-22-class error is subdominant (model: ~1e-4 at the output).
// ---------------------------------------------------------------------------
__global__ __launch_bounds__(256) void split_f16_k(
    const float* __restrict__ s, _Float16* __restrict__ hi,
    _Float16* __restrict__ lo, int n4) {
  int i = blockIdx.x * 256 + threadIdx.x;
  if (i >= n4) return;
  float4 a = ((const float4*)s)[i];
  half4 h, l;
  float av[4] = {a.x, a.y, a.z, a.w};
#pragma unroll
  for (int j = 0; j < 4; ++j) {
    _Float16 hh = (_Float16)av[j];
    h[j] = hh;
    l[j] = (_Float16)((av[j] - (float)hh) * 2048.0f);
  }
  ((half4*)hi)[i] = h;
  ((half4*)lo)[i] = l;
}

// ---------------------------------------------------------------------------
// Split-f16 NT GEMM via MFMA 16x16x32_f16 (GEMM2 only).
// C = AhBh + 2^-11 (Ah*Bl' + Al'*Bh). BM=128, BN=64, BK=32, 4 waves.
// ---------------------------------------------------------------------------
__global__ __launch_bounds__(256) void gemm_split_nt(
    const _Float16* __restrict__ Ah, const _Float16* __restrict__ Al,
    const _Float16* __restrict__ Bh, const _Float16* __restrict__ Bl,
    const float* __restrict__ bias, float* __restrict__ C,
    int Ndim, int Kd) {
  constexpr int BM = 128, BN = 64, BK = 32;
  __shared__ _Float16 lds[(2 * BM + 2 * BN) * BK];  // 24 KB
  constexpr int AHo = 0;
  constexpr int ALo = BM * BK;
  constexpr int BHo = 2 * BM * BK;
  constexpr int BLo = 2 * BM * BK + BN * BK;

  const int tid = threadIdx.x;
  const int wave = tid >> 6, lane = tid & 63;
  const int lq = lane >> 4, lm = lane & 15;
  const int bm = blockIdx.y * BM, bn = blockIdx.x * BN;

  f32x4 acc[2][4] = {};
  f32x4 corr[2][4] = {};

  const int nsteps = Kd >> 5;
  for (int ks = 0; ks < nsteps; ++ks) {
    const int k0 = ks * BK;
    for (int idx = wave; idx < 24; idx += 4) {
      int t, j;
      if (idx < 8)       { t = 0; j = idx; }
      else if (idx < 16) { t = 1; j = idx - 8; }
      else if (idx < 20) { t = 2; j = idx - 16; }
      else               { t = 3; j = idx - 20; }
      const int row = j * 16 + (lane >> 2);
      const _Float16* g;
      _Float16* l;
      if (t == 0)      { g = Ah + (size_t)(bm + row) * Kd; l = lds + AHo + j * 16 * BK; }
      else if (t == 1) { g = Al + (size_t)(bm + row) * Kd; l = lds + ALo + j * 16 * BK; }
      else if (t == 2) { g = Bh + (size_t)(bn + row) * Kd; l = lds + BHo + j * 16 * BK; }
      else             { g = Bl + (size_t)(bn + row) * Kd; l = lds + BLo + j * 16 * BK; }
      g += k0 + (lane & 3) * 8;
      __builtin_amdgcn_global_load_lds(AS1(g), AS3(l), 16, 0, 0);
    }
    __syncthreads();

    half8 ahf[2], alf[2], bhf[4], blf[4];
    const int mwo = wave * 32;
#pragma unroll
    for (int fi = 0; fi < 2; ++fi) {
      ahf[fi] = *(const half8*)&lds[AHo + (mwo + fi * 16 + lm) * BK + lq * 8];
      alf[fi] = *(const half8*)&lds[ALo + (mwo + fi * 16 + lm) * BK + lq * 8];
    }
#pragma unroll
    for (int fj = 0; fj < 4; ++fj) {
      bhf[fj] = *(const half8*)&lds[BHo + (fj * 16 + lm) * BK + lq * 8];
      blf[fj] = *(const half8*)&lds[BLo + (fj * 16 + lm) * BK + lq * 8];
    }
#pragma unroll
    for (int fi = 0; fi < 2; ++fi)
#pragma unroll
      for (int fj = 0; fj < 4; ++fj) {
        acc[fi][fj] = __builtin_amdgcn_mfma_f32_16x16x32_f16(
            ahf[fi], bhf[fj], acc[fi][fj], 0, 0, 0);
        corr[fi][fj] = __builtin_amdgcn_mfma_f32_16x16x32_f16(
            ahf[fi], blf[fj], corr[fi][fj], 0, 0, 0);
        corr[fi][fj] = __builtin_amdgcn_mfma_f32_16x16x32_f16(
            alf[fi], bhf[fj], corr[fi][fj], 0, 0, 0);
      }
    __syncthreads();
  }

  // Epilogue: C/D layout col = lane&15, row = quad*4 + reg
#pragma unroll
  for (int fi = 0; fi < 2; ++fi) {
    const int m0 = bm + wave * 32 + fi * 16 + lq * 4;
#pragma unroll
    for (int fj = 0; fj < 4; ++fj) {
      const int n = bn + fj * 16 + lm;
      const float bb = bias ? bias[n] : 0.f;
      f32x4 v = acc[fi][fj];
      f32x4 cv = corr[fi][fj];
#pragma unroll
      for (int r = 0; r < 4; ++r)
        C[(size_t)(m0 + r) * Ndim + n] = v[r] + cv[r] * (1.0f / 2048.0f) + bb;
    }
  }
}

// ---------------------------------------------------------------------------
// Per-head LayerNorm over D=64 on the k and v segments of qkv, in place.
// ---------------------------------------------------------------------------
__global__ __launch_bounds__(256) void ln_kv(
    float* __restrict__ qkv,
    const float* __restrict__ lnk_w, const float* __restrict__ lnk_b,
    const float* __restrict__ lnv_w, const float* __restrict__ lnv_b) {
  int wave = (blockIdx.x * 256 + threadIdx.x) >> 6;
  int lane = threadIdx.x & 63;
  const int total = Bb * Nn * Hh;
  bool isv = wave >= total;
  int r = isv ? wave - total : wave;
  int bn = r / Hh, h = r % Hh;
  float* p = qkv + (size_t)bn * TQKV + (isv ? 2 * INNER : INNER) + h * Dd + lane;
  float val = *p;
  float s = val, s2 = val * val;
#pragma unroll
  for (int off = 32; off; off >>= 1) {
    s += __shfl_xor(s, off, 64);
    s2 += __shfl_xor(s2, off, 64);
  }
  float mean = s * (1.f / 64.f);
  float var = s2 * (1.f / 64.f) - mean * mean;
  float inv = 1.0f / sqrtf(var + EPSF);
  const float* w = isv ? lnv_w : lnk_w;
  const float* b = isv ? lnv_b : lnk_b;
  *p = (val - mean) * inv * w[h * Dd + lane] + b[h * Dd + lane];
}

// ---------------------------------------------------------------------------
// Pass 1: per-chunk S_c = K_c^T V_c [64x64] and kc_c = colsum(K_c) [64].
// ---------------------------------------------------------------------------
__global__ __launch_bounds__(256) void chunk_sums(
    const float* __restrict__ qkv, float* __restrict__ cbuf) {
  int blk = blockIdx.x;
  int c = blk % NCH;
  int bh = blk / NCH;
  int h = bh % Hh, b = bh / Hh;
  __shared__ float Ks[CH][68];
  __shared__ float Vs[CH][68];
  int tid = threadIdx.x;
  const float* base = qkv + (size_t)(b * Nn + c * CH) * TQKV + h * Dd;
  for (int i = tid; i < CH * 16; i += 256) {
    int row = i >> 4, c4 = i & 15;
    *(float4*)&Ks[row][c4 * 4] =
        *(const float4*)(base + (size_t)row * TQKV + INNER + c4 * 4);
    *(float4*)&Vs[row][c4 * 4] =
        *(const float4*)(base + (size_t)row * TQKV + 2 * INNER + c4 * 4);
  }
  __syncthreads();
  int d0 = (tid >> 4) * 4, e0 = (tid & 15) * 4;
  float acc[4][4] = {};
  float kc[4] = {0.f, 0.f, 0.f, 0.f};
  for (int n = 0; n < CH; ++n) {
    float4 kv = *(const float4*)&Ks[n][d0];
    float4 vv = *(const float4*)&Vs[n][e0];
    float ka[4] = {kv.x, kv.y, kv.z, kv.w};
    float va[4] = {vv.x, vv.y, vv.z, vv.w};
#pragma unroll
    for (int i = 0; i < 4; ++i)
#pragma unroll
      for (int j = 0; j < 4; ++j) acc[i][j] += ka[i] * va[j];
    if (e0 == 0) {
#pragma unroll
      for (int i = 0; i < 4; ++i) kc[i] += ka[i];
    }
  }
  float* out = cbuf + (size_t)blk * CSZ;
#pragma unroll
  for (int i = 0; i < 4; ++i) {
    float4 r;
    r.x = acc[i][0]; r.y = acc[i][1]; r.z = acc[i][2]; r.w = acc[i][3];
    *(float4*)(out + (size_t)(d0 + i) * Dd + e0) = r;
  }
  if (e0 == 0) {
#pragma unroll
    for (int i = 0; i < 4; ++i) out[Dd * Dd + d0 + i] = kc[i];
  }
}

// ---------------------------------------------------------------------------
// Pass 2: exclusive prefix over chunks. Parallel over columns now:
// grid (ceil(CSZ/256), Bb*Hh) instead of 16 blocks total.
// ---------------------------------------------------------------------------
__global__ __launch_bounds__(256) void chunk_prefix(float* __restrict__ cbuf) {
  int bh = blockIdx.y;
  int i = blockIdx.x * 256 + threadIdx.x;
  if (i >= CSZ) return;
  float* p = cbuf + (size_t)bh * NCH * CSZ + i;
  float carry = 0.f;
  for (int c = 0; c < NCH; ++c) {
    float t = p[(size_t)c * CSZ];
    p[(size_t)c * CSZ] = carry;
    carry += t;
  }
}

// ---------------------------------------------------------------------------
// Pass 3: per chunk attention; writes attn split to f16 hi/lo for GEMM2.
// ---------------------------------------------------------------------------
__global__ __launch_bounds__(256) void chunk_attn(
    const float* __restrict__ qkv, const float* __restrict__ cbuf,
    _Float16* __restrict__ atth, _Float16* __restrict__ attl) {
  int blk = blockIdx.x;
  int c = blk % NCH;
  int bh = blk / NCH;
  int h = bh % Hh, b = bh / Hh;
  __shared__ float Qs[64][68];   // [d][n] transposed
  __shared__ float Ks[64][68];   // [d][m] transposed
  __shared__ float Vs[64][68];   // [m][e]
  __shared__ float Ps[64][68];   // [m][n] masked P
  __shared__ float Ss[64][68];   // [d][e] S_prefix
  __shared__ float kcs[64];
  __shared__ float rs[64][17];
  __shared__ float denomS[64];

  int tid = threadIdx.x;
  int tx = tid & 15, ty = tid >> 4;
  const float* base = qkv + (size_t)(b * Nn + c * CH) * TQKV + h * Dd;
  for (int i = tid; i < CH * 16; i += 256) {
    int row = i >> 4, c4 = i & 15;
    float4 fq = *(const float4*)(base + (size_t)row * TQKV + c4 * 4);
    Qs[c4 * 4 + 0][row] = fq.x; Qs[c4 * 4 + 1][row] = fq.y;
    Qs[c4 * 4 + 2][row] = fq.z; Qs[c4 * 4 + 3][row] = fq.w;
    float4 fk = *(const float4*)(base + (size_t)row * TQKV + INNER + c4 * 4);
    Ks[c4 * 4 + 0][row] = fk.x; Ks[c4 * 4 + 1][row] = fk.y;
    Ks[c4 * 4 + 2][row] = fk.z; Ks[c4 * 4 + 3][row] = fk.w;
    float4 fv = *(const float4*)(base + (size_t)row * TQKV + 2 * INNER + c4 * 4);
    *(float4*)&Vs[row][c4 * 4] = fv;
  }
  const float* sp = cbuf + (size_t)blk * CSZ;
  for (int i = tid; i < 1024; i += 256) {
    int row = i >> 4;
    *(float4*)&Ss[row][(i & 15) * 4] = *(const float4*)(sp + (size_t)i * 4);
  }
  if (tid < 16) {
    float4 f = *(const float4*)(sp + Dd * Dd + tid * 4);
    kcs[tid * 4 + 0] = f.x; kcs[tid * 4 + 1] = f.y;
    kcs[tid * 4 + 2] = f.z; kcs[tid * 4 + 3] = f.w;
  }
  __syncthreads();

  // P = Q K^T, causal mask, rowsum
  float accP[4][4] = {};
  for (int kk = 0; kk < 64; ++kk) {
    float4 qa = *(const float4*)&Qs[kk][ty * 4];
    float4 kb = *(const float4*)&Ks[kk][tx * 4];
    float qv[4] = {qa.x, qa.y, qa.z, qa.w};
    float kv[4] = {kb.x, kb.y, kb.z, kb.w};
#pragma unroll
    for (int i = 0; i < 4; ++i)
#pragma unroll
      for (int j = 0; j < 4; ++j) accP[i][j] += qv[i] * kv[j];
  }
#pragma unroll
  for (int i = 0; i < 4; ++i) {
    int n = ty * 4 + i;
    float rsum = 0.f;
#pragma unroll
    for (int j = 0; j < 4; ++j) {
      int m = tx * 4 + j;
      float p = (m <= n) ? accP[i][j] : 0.f;
      Ps[m][n] = p;
      rsum += p;
    }
    rs[n][tx] = rsum;
  }
  __syncthreads();

  // O = Q * S_prefix; denom
  float accO[4][4] = {};
  for (int d = 0; d < 64; ++d) {
    float4 qa = *(const float4*)&Qs[d][ty * 4];
    float4 sb = *(const float4*)&Ss[d][tx * 4];
    float qv[4] = {qa.x, qa.y, qa.z, qa.w};
    float sv[4] = {sb.x, sb.y, sb.z, sb.w};
#pragma unroll
    for (int i = 0; i < 4; ++i)
#pragma unroll
      for (int j = 0; j < 4; ++j) accO[i][j] += qv[i] * sv[j];
  }
  if (tid < 64) {
    int n = tid;
    float qkc = 0.f, qs = 0.f;
    for (int d = 0; d < 64; ++d) {
      float q = Qs[d][n];
      qkc += q * kcs[d];
      qs += q;
    }
    float rsum = 0.f;
#pragma unroll
    for (int t2 = 0; t2 < 16; ++t2) rsum += rs[n][t2];
    denomS[n] = qkc + rsum + EPSF * qs;
  }
  __syncthreads();

  // O += P_masked * V
  for (int m = 0; m < 64; ++m) {
    float4 pa = *(const float4*)&Ps[m][ty * 4];
    float4 vb = *(const float4*)&Vs[m][tx * 4];
    float pv[4] = {pa.x, pa.y, pa.z, pa.w};
    float vv[4] = {vb.x, vb.y, vb.z, vb.w};
#pragma unroll
    for (int i = 0; i < 4; ++i)
#pragma unroll
      for (int j = 0; j < 4; ++j) accO[i][j] += pv[i] * vv[j];
  }

  size_t obase = (size_t)(b * Nn + c * CH) * INNER + h * Dd;
#pragma unroll
  for (int i = 0; i < 4; ++i) {
    int n = ty * 4 + i;
    float dinv = 1.0f / denomS[n];
    float scale = dinv * (1.0f / (float)Nn);
    half4 hv, lv;
#pragma unroll
    for (int j = 0; j < 4; ++j) {
      float o = accO[i][j] * scale;
      _Float16 hh = (_Float16)o;
      hv[j] = hh;
      lv[j] = (_Float16)((o - (float)hh) * 2048.0f);
    }
    *(half4*)(atth + obase + (size_t)n * INNER + tx * 4) = hv;
    *(half4*)(attl + obase + (size_t)n * INNER + tx * 4) = lv;
  }
}

// ---------------------------------------------------------------------------
extern "C" void kernel_launch(void* const* d_in, const int* in_sizes, int n_in,
                              void* d_out, int out_size, void* d_ws,
                              size_t ws_size, hipStream_t stream) {
  const float* x     = (const float*)d_in[0];
  const float* w_qkv = (const float*)d_in[1];
  const float* lnk_w = (const float*)d_in[2];
  const float* lnk_b = (const float*)d_in[3];
  const float* lnv_w = (const float*)d_in[4];
  const float* lnv_b = (const float*)d_in[5];
  const float* w_out = (const float*)d_in[6];
  const float* b_out = (const float*)d_in[7];
  float* out = (float*)d_out;

  // Workspace layout (~43 MB):
  float* qkv  = (float*)d_ws;                      // 4096*1536 fp32
  float* cbuf = qkv + (size_t)Mm * TQKV;           // 512*4160 fp32
  _Float16* atth = (_Float16*)(cbuf + (size_t)Bb * Hh * NCH * CSZ);
  _Float16* attl = atth + (size_t)Mm * INNER;
  _Float16* woh  = attl + (size_t)Mm * INNER;
  _Float16* wol  = woh + (size_t)INNER * 512;

  // 1. QKV GEMM (fp32, R1-identical numerics, 64-tile for occupancy)
  gemm_nt<64><<<dim3(TQKV / 64, Mm / 64), 256, 0, stream>>>(
      x, w_qkv, nullptr, qkv, Mm, TQKV, 512);

  // 2. Per-head LayerNorm on k, v (in place, fp32)
  ln_kv<<<(2 * Bb * Nn * Hh * 64) / 256, 256, 0, stream>>>(
      qkv, lnk_w, lnk_b, lnv_w, lnv_b);

  // 3. Per-chunk K^T V and colsum(K)
  chunk_sums<<<Bb * Hh * NCH, 256, 0, stream>>>(qkv, cbuf);

  // 4. Exclusive prefix over chunks (parallel over columns)
  chunk_prefix<<<dim3((CSZ + 255) / 256, Bb * Hh), 256, 0, stream>>>(cbuf);

  // 5. Split w_out for GEMM2
  split_f16_k<<<256, 256, 0, stream>>>(w_out, woh, wol, INNER * 512 / 4);

  // 6. Per-chunk attention -> attn split f16
  chunk_attn<<<Bb * Hh * NCH, 256, 0, stream>>>(qkv, cbuf, atth, attl);

  // 7. Output GEMM: out = attn * w_out^T + b_out (split-f16 MFMA)
  gemm_split_nt<<<dim3(INNER / 64, Mm / 128), 256, 0, stream>>>(
      atth, attl, woh, wol, b_out, out, INNER, 512);
}

// Round 7
// 237.390 us; speedup vs baseline: 1.2398x; 1.0292x over previous
//
#include <hip/hip_runtime.h>

// Problem constants
constexpr int Bb   = 2;
constexpr int Nn   = 2048;
constexpr int Hh   = 8;
constexpr int Dd   = 64;
constexpr int Mm   = Bb * Nn;      // 4096 rows
constexpr int TQKV = 1536;         // 3 * H * D
constexpr int INNER = Hh * Dd;     // 512
constexpr int CH   = 64;           // chunk length
constexpr int NCH  = Nn / CH;      // 32 chunks per (b,h)
constexpr int CSZ  = Dd * Dd + Dd; // 4160 floats per chunk record (S + kc)
constexpr float EPSF = 1e-7f;

typedef _Float16 half8 __attribute__((ext_vector_type(8)));
typedef _Float16 half4 __attribute__((ext_vector_type(4)));
typedef float f32x4 __attribute__((ext_vector_type(4)));

#define AS1(p) ((const __attribute__((address_space(1))) unsigned int*)(p))
#define AS3(p) ((__attribute__((address_space(3))) unsigned int*)(p))

// ---------------------------------------------------------------------------
// GEMM1 (fp32 VALU): qkv[4096,1536] = x[4096,512] * w_qkv[1536,512]^T.
// R2-R6 verdict: ANY f16-split MFMA scheme for q/k fails the 1e5-amplified
// denominator (missing AlBl cross term + in-MFMA accumulation rounding);
// fp32 sequential accumulation is required. This kernel keeps R4 numerics
// (same k-order, FMA-contracted) but fixes R4's measured inefficiencies:
//  - 128x64 tile, 8x4/thread: 32 FMA vs 3 ds_read_b128 per kk (VALU-bound;
//    R4's 64^2 tile was 16 FMA vs 2 reads -> LDS-read-bound, VALUBusy 50%)
//  - staging lane map row=tid&127: banks 2-way only (R4: 4-way, 9.4M conflicts)
//  - BK=32 halves barrier count vs R4's BK=16
// ---------------------------------------------------------------------------
__global__ __launch_bounds__(256) void gemm1_f32(
    const float* __restrict__ A, const float* __restrict__ B,
    float* __restrict__ C) {
  __shared__ float As[32][132];  // [k][m], stride 132: write banks 2-way free
  __shared__ float Bs[32][68];   // [k][n]
  const int tid = threadIdx.x;
  const int tx = tid & 15, ty = tid >> 4;
  const int bm = blockIdx.y * 128, bn = blockIdx.x * 64;
  const int rowA = tid & 127, c4a = tid >> 7;  // 0..1
  const int rowB = tid & 63,  c4b = tid >> 6;  // 0..3

  float acc[8][4] = {};

  for (int k0 = 0; k0 < 512; k0 += 32) {
#pragma unroll
    for (int p = 0; p < 4; ++p) {
      int c4 = c4a + 2 * p;
      float4 fa = *(const float4*)(A + (size_t)(bm + rowA) * 512 + k0 + c4 * 4);
      As[c4 * 4 + 0][rowA] = fa.x; As[c4 * 4 + 1][rowA] = fa.y;
      As[c4 * 4 + 2][rowA] = fa.z; As[c4 * 4 + 3][rowA] = fa.w;
    }
#pragma unroll
    for (int p = 0; p < 2; ++p) {
      int c4 = c4b + 4 * p;
      float4 fb = *(const float4*)(B + (size_t)(bn + rowB) * 512 + k0 + c4 * 4);
      Bs[c4 * 4 + 0][rowB] = fb.x; Bs[c4 * 4 + 1][rowB] = fb.y;
      Bs[c4 * 4 + 2][rowB] = fb.z; Bs[c4 * 4 + 3][rowB] = fb.w;
    }
    __syncthreads();
#pragma unroll
    for (int kk = 0; kk < 32; ++kk) {
      float a[8], b[4];
      *(float4*)&a[0] = *(const float4*)&As[kk][ty * 8];
      *(float4*)&a[4] = *(const float4*)&As[kk][ty * 8 + 4];
      *(float4*)&b[0] = *(const float4*)&Bs[kk][tx * 4];
#pragma unroll
      for (int i = 0; i < 8; ++i)
#pragma unroll
        for (int j = 0; j < 4; ++j) acc[i][j] += a[i] * b[j];
    }
    __syncthreads();
  }

#pragma unroll
  for (int i = 0; i < 8; ++i) {
    size_t row = bm + ty * 8 + i;
    float4 r;
    r.x = acc[i][0]; r.y = acc[i][1]; r.z = acc[i][2]; r.w = acc[i][3];
    *(float4*)(C + row * (size_t)TQKV + bn + tx * 4) = r;
  }
}

// ---------------------------------------------------------------------------
// 2-way split fp32 -> (hi, lo*2^11) for GEMM2 operands (validated: R4 absmax
// bit-equal to all-fp32 -> GEMM2's split error is subdominant).
// ---------------------------------------------------------------------------
__global__ __launch_bounds__(256) void split_f16_k(
    const float* __restrict__ s, _Float16* __restrict__ hi,
    _Float16* __restrict__ lo, int n4) {
  int i = blockIdx.x * 256 + threadIdx.x;
  if (i >= n4) return;
  float4 a = ((const float4*)s)[i];
  half4 h, l;
  float av[4] = {a.x, a.y, a.z, a.w};
#pragma unroll
  for (int j = 0; j < 4; ++j) {
    _Float16 hh = (_Float16)av[j];
    h[j] = hh;
    l[j] = (_Float16)((av[j] - (float)hh) * 2048.0f);
  }
  ((half4*)hi)[i] = h;
  ((half4*)lo)[i] = l;
}

// ---------------------------------------------------------------------------
// 2-term split-f16 NT GEMM via MFMA (GEMM2 ONLY — R4-exact, proven passing).
// ---------------------------------------------------------------------------
__global__ __launch_bounds__(256) void gemm_split_nt(
    const _Float16* __restrict__ Ah, const _Float16* __restrict__ Al,
    const _Float16* __restrict__ Bh, const _Float16* __restrict__ Bl,
    const float* __restrict__ bias, float* __restrict__ C,
    int Ndim, int Kd) {
  constexpr int BM = 128, BN = 64, BK = 32;
  __shared__ _Float16 lds[(2 * BM + 2 * BN) * BK];  // 24 KB
  constexpr int AHo = 0;
  constexpr int ALo = BM * BK;
  constexpr int BHo = 2 * BM * BK;
  constexpr int BLo = 2 * BM * BK + BN * BK;

  const int tid = threadIdx.x;
  const int wave = tid >> 6, lane = tid & 63;
  const int lq = lane >> 4, lm = lane & 15;
  const int bm = blockIdx.y * BM, bn = blockIdx.x * BN;

  f32x4 acc[2][4] = {};
  f32x4 corr[2][4] = {};

  const int nsteps = Kd >> 5;
  for (int ks = 0; ks < nsteps; ++ks) {
    const int k0 = ks * BK;
    for (int idx = wave; idx < 24; idx += 4) {
      int t, j;
      if (idx < 8)       { t = 0; j = idx; }
      else if (idx < 16) { t = 1; j = idx - 8; }
      else if (idx < 20) { t = 2; j = idx - 16; }
      else               { t = 3; j = idx - 20; }
      const int row = j * 16 + (lane >> 2);
      const _Float16* g;
      _Float16* l;
      if (t == 0)      { g = Ah + (size_t)(bm + row) * Kd; l = lds + AHo + j * 16 * BK; }
      else if (t == 1) { g = Al + (size_t)(bm + row) * Kd; l = lds + ALo + j * 16 * BK; }
      else if (t == 2) { g = Bh + (size_t)(bn + row) * Kd; l = lds + BHo + j * 16 * BK; }
      else             { g = Bl + (size_t)(bn + row) * Kd; l = lds + BLo + j * 16 * BK; }
      g += k0 + (lane & 3) * 8;
      __builtin_amdgcn_global_load_lds(AS1(g), AS3(l), 16, 0, 0);
    }
    __syncthreads();

    half8 ahf[2], alf[2], bhf[4], blf[4];
    const int mwo = wave * 32;
#pragma unroll
    for (int fi = 0; fi < 2; ++fi) {
      ahf[fi] = *(const half8*)&lds[AHo + (mwo + fi * 16 + lm) * BK + lq * 8];
      alf[fi] = *(const half8*)&lds[ALo + (mwo + fi * 16 + lm) * BK + lq * 8];
    }
#pragma unroll
    for (int fj = 0; fj < 4; ++fj) {
      bhf[fj] = *(const half8*)&lds[BHo + (fj * 16 + lm) * BK + lq * 8];
      blf[fj] = *(const half8*)&lds[BLo + (fj * 16 + lm) * BK + lq * 8];
    }
#pragma unroll
    for (int fi = 0; fi < 2; ++fi)
#pragma unroll
      for (int fj = 0; fj < 4; ++fj) {
        acc[fi][fj] = __builtin_amdgcn_mfma_f32_16x16x32_f16(
            ahf[fi], bhf[fj], acc[fi][fj], 0, 0, 0);
        corr[fi][fj] = __builtin_amdgcn_mfma_f32_16x16x32_f16(
            ahf[fi], blf[fj], corr[fi][fj], 0, 0, 0);
        corr[fi][fj] = __builtin_amdgcn_mfma_f32_16x16x32_f16(
            alf[fi], bhf[fj], corr[fi][fj], 0, 0, 0);
      }
    __syncthreads();
  }

  // Epilogue: C/D layout col = lane&15, row = quad*4 + reg
#pragma unroll
  for (int fi = 0; fi < 2; ++fi) {
    const int m0 = bm + wave * 32 + fi * 16 + lq * 4;
#pragma unroll
    for (int fj = 0; fj < 4; ++fj) {
      const int n = bn + fj * 16 + lm;
      const float bb = bias ? bias[n] : 0.f;
      f32x4 v = acc[fi][fj];
      f32x4 cv = corr[fi][fj];
#pragma unroll
      for (int r = 0; r < 4; ++r)
        C[(size_t)(m0 + r) * Ndim + n] = v[r] + cv[r] * (1.0f / 2048.0f) + bb;
    }
  }
}

// ---------------------------------------------------------------------------
// Per-head LayerNorm over D=64 on the k and v segments of qkv, in place.
// ---------------------------------------------------------------------------
__global__ __launch_bounds__(256) void ln_kv(
    float* __restrict__ qkv,
    const float* __restrict__ lnk_w, const float* __restrict__ lnk_b,
    const float* __restrict__ lnv_w, const float* __restrict__ lnv_b) {
  int wave = (blockIdx.x * 256 + threadIdx.x) >> 6;
  int lane = threadIdx.x & 63;
  const int total = Bb * Nn * Hh;
  bool isv = wave >= total;
  int r = isv ? wave - total : wave;
  int bn = r / Hh, h = r % Hh;
  float* p = qkv + (size_t)bn * TQKV + (isv ? 2 * INNER : INNER) + h * Dd + lane;
  float val = *p;
  float s = val, s2 = val * val;
#pragma unroll
  for (int off = 32; off; off >>= 1) {
    s += __shfl_xor(s, off, 64);
    s2 += __shfl_xor(s2, off, 64);
  }
  float mean = s * (1.f / 64.f);
  float var = s2 * (1.f / 64.f) - mean * mean;
  float inv = 1.0f / sqrtf(var + EPSF);
  const float* w = isv ? lnv_w : lnk_w;
  const float* b = isv ? lnv_b : lnk_b;
  *p = (val - mean) * inv * w[h * Dd + lane] + b[h * Dd + lane];
}

// ---------------------------------------------------------------------------
// Pass 1: per-chunk S_c = K_c^T V_c [64x64] and kc_c = colsum(K_c) [64].
// ---------------------------------------------------------------------------
__global__ __launch_bounds__(256) void chunk_sums(
    const float* __restrict__ qkv, float* __restrict__ cbuf) {
  int blk = blockIdx.x;
  int c = blk % NCH;
  int bh = blk / NCH;
  int h = bh % Hh, b = bh / Hh;
  __shared__ float Ks[CH][68];
  __shared__ float Vs[CH][68];
  int tid = threadIdx.x;
  const float* base = qkv + (size_t)(b * Nn + c * CH) * TQKV + h * Dd;
  for (int i = tid; i < CH * 16; i += 256) {
    int row = i >> 4, c4 = i & 15;
    *(float4*)&Ks[row][c4 * 4] =
        *(const float4*)(base + (size_t)row * TQKV + INNER + c4 * 4);
    *(float4*)&Vs[row][c4 * 4] =
        *(const float4*)(base + (size_t)row * TQKV + 2 * INNER + c4 * 4);
  }
  __syncthreads();
  int d0 = (tid >> 4) * 4, e0 = (tid & 15) * 4;
  float acc[4][4] = {};
  float kc[4] = {0.f, 0.f, 0.f, 0.f};
  for (int n = 0; n < CH; ++n) {
    float4 kv = *(const float4*)&Ks[n][d0];
    float4 vv = *(const float4*)&Vs[n][e0];
    float ka[4] = {kv.x, kv.y, kv.z, kv.w};
    float va[4] = {vv.x, vv.y, vv.z, vv.w};
#pragma unroll
    for (int i = 0; i < 4; ++i)
#pragma unroll
      for (int j = 0; j < 4; ++j) acc[i][j] += ka[i] * va[j];
    if (e0 == 0) {
#pragma unroll
      for (int i = 0; i < 4; ++i) kc[i] += ka[i];
    }
  }
  float* out = cbuf + (size_t)blk * CSZ;
#pragma unroll
  for (int i = 0; i < 4; ++i) {
    float4 r;
    r.x = acc[i][0]; r.y = acc[i][1]; r.z = acc[i][2]; r.w = acc[i][3];
    *(float4*)(out + (size_t)(d0 + i) * Dd + e0) = r;
  }
  if (e0 == 0) {
#pragma unroll
    for (int i = 0; i < 4; ++i) out[Dd * Dd + d0 + i] = kc[i];
  }
}

// ---------------------------------------------------------------------------
// Pass 2: exclusive prefix over chunks, parallel over columns.
// ---------------------------------------------------------------------------
__global__ __launch_bounds__(256) void chunk_prefix(float* __restrict__ cbuf) {
  int bh = blockIdx.y;
  int i = blockIdx.x * 256 + threadIdx.x;
  if (i >= CSZ) return;
  float* p = cbuf + (size_t)bh * NCH * CSZ + i;
  float carry = 0.f;
  for (int c = 0; c < NCH; ++c) {
    float t = p[(size_t)c * CSZ];
    p[(size_t)c * CSZ] = carry;
    carry += t;
  }
}

// ---------------------------------------------------------------------------
// Pass 3: per chunk attention; writes attn split to f16 hi/lo for GEMM2.
// ---------------------------------------------------------------------------
__global__ __launch_bounds__(256) void chunk_attn(
    const float* __restrict__ qkv, const float* __restrict__ cbuf,
    _Float16* __restrict__ atth, _Float16* __restrict__ attl) {
  int blk = blockIdx.x;
  int c = blk % NCH;
  int bh = blk / NCH;
  int h = bh % Hh, b = bh / Hh;
  __shared__ float Qs[64][68];   // [d][n] transposed
  __shared__ float Ks[64][68];   // [d][m] transposed
  __shared__ float Vs[64][68];   // [m][e]
  __shared__ float Ps[64][68];   // [m][n] masked P
  __shared__ float Ss[64][68];   // [d][e] S_prefix
  __shared__ float kcs[64];
  __shared__ float rs[64][17];
  __shared__ float denomS[64];

  int tid = threadIdx.x;
  int tx = tid & 15, ty = tid >> 4;
  const float* base = qkv + (size_t)(b * Nn + c * CH) * TQKV + h * Dd;
  for (int i = tid; i < CH * 16; i += 256) {
    int row = i >> 4, c4 = i & 15;
    float4 fq = *(const float4*)(base + (size_t)row * TQKV + c4 * 4);
    Qs[c4 * 4 + 0][row] = fq.x; Qs[c4 * 4 + 1][row] = fq.y;
    Qs[c4 * 4 + 2][row] = fq.z; Qs[c4 * 4 + 3][row] = fq.w;
    float4 fk = *(const float4*)(base + (size_t)row * TQKV + INNER + c4 * 4);
    Ks[c4 * 4 + 0][row] = fk.x; Ks[c4 * 4 + 1][row] = fk.y;
    Ks[c4 * 4 + 2][row] = fk.z; Ks[c4 * 4 + 3][row] = fk.w;
    float4 fv = *(const float4*)(base + (size_t)row * TQKV + 2 * INNER + c4 * 4);
    *(float4*)&Vs[row][c4 * 4] = fv;
  }
  const float* sp = cbuf + (size_t)blk * CSZ;
  for (int i = tid; i < 1024; i += 256) {
    int row = i >> 4;
    *(float4*)&Ss[row][(i & 15) * 4] = *(const float4*)(sp + (size_t)i * 4);
  }
  if (tid < 16) {
    float4 f = *(const float4*)(sp + Dd * Dd + tid * 4);
    kcs[tid * 4 + 0] = f.x; kcs[tid * 4 + 1] = f.y;
    kcs[tid * 4 + 2] = f.z; kcs[tid * 4 + 3] = f.w;
  }
  __syncthreads();

  // P = Q K^T, causal mask, rowsum
  float accP[4][4] = {};
  for (int kk = 0; kk < 64; ++kk) {
    float4 qa = *(const float4*)&Qs[kk][ty * 4];
    float4 kb = *(const float4*)&Ks[kk][tx * 4];
    float qv[4] = {qa.x, qa.y, qa.z, qa.w};
    float kv[4] = {kb.x, kb.y, kb.z, kb.w};
#pragma unroll
    for (int i = 0; i < 4; ++i)
#pragma unroll
      for (int j = 0; j < 4; ++j) accP[i][j] += qv[i] * kv[j];
  }
#pragma unroll
  for (int i = 0; i < 4; ++i) {
    int n = ty * 4 + i;
    float rsum = 0.f;
#pragma unroll
    for (int j = 0; j < 4; ++j) {
      int m = tx * 4 + j;
      float p = (m <= n) ? accP[i][j] : 0.f;
      Ps[m][n] = p;
      rsum += p;
    }
    rs[n][tx] = rsum;
  }
  __syncthreads();

  // O = Q * S_prefix; denom
  float accO[4][4] = {};
  for (int d = 0; d < 64; ++d) {
    float4 qa = *(const float4*)&Qs[d][ty * 4];
    float4 sb = *(const float4*)&Ss[d][tx * 4];
    float qv[4] = {qa.x, qa.y, qa.z, qa.w};
    float sv[4] = {sb.x, sb.y, sb.z, sb.w};
#pragma unroll
    for (int i = 0; i < 4; ++i)
#pragma unroll
      for (int j = 0; j < 4; ++j) accO[i][j] += qv[i] * sv[j];
  }
  if (tid < 64) {
    int n = tid;
    float qkc = 0.f, qs = 0.f;
    for (int d = 0; d < 64; ++d) {
      float q = Qs[d][n];
      qkc += q * kcs[d];
      qs += q;
    }
    float rsum = 0.f;
#pragma unroll
    for (int t2 = 0; t2 < 16; ++t2) rsum += rs[n][t2];
    denomS[n] = qkc + rsum + EPSF * qs;
  }
  __syncthreads();

  // O += P_masked * V
  for (int m = 0; m < 64; ++m) {
    float4 pa = *(const float4*)&Ps[m][ty * 4];
    float4 vb = *(const float4*)&Vs[m][tx * 4];
    float pv[4] = {pa.x, pa.y, pa.z, pa.w};
    float vv[4] = {vb.x, vb.y, vb.z, vb.w};
#pragma unroll
    for (int i = 0; i < 4; ++i)
#pragma unroll
      for (int j = 0; j < 4; ++j) accO[i][j] += pv[i] * vv[j];
  }

  size_t obase = (size_t)(b * Nn + c * CH) * INNER + h * Dd;
#pragma unroll
  for (int i = 0; i < 4; ++i) {
    int n = ty * 4 + i;
    float dinv = 1.0f / denomS[n];
    float scale = dinv * (1.0f / (float)Nn);
    half4 hv, lv;
#pragma unroll
    for (int j = 0; j < 4; ++j) {
      float o = accO[i][j] * scale;
      _Float16 hh = (_Float16)o;
      hv[j] = hh;
      lv[j] = (_Float16)((o - (float)hh) * 2048.0f);
    }
    *(half4*)(atth + obase + (size_t)n * INNER + tx * 4) = hv;
    *(half4*)(attl + obase + (size_t)n * INNER + tx * 4) = lv;
  }
}

// ---------------------------------------------------------------------------
extern "C" void kernel_launch(void* const* d_in, const int* in_sizes, int n_in,
                              void* d_out, int out_size, void* d_ws,
                              size_t ws_size, hipStream_t stream) {
  const float* x     = (const float*)d_in[0];
  const float* w_qkv = (const float*)d_in[1];
  const float* lnk_w = (const float*)d_in[2];
  const float* lnk_b = (const float*)d_in[3];
  const float* lnv_w = (const float*)d_in[4];
  const float* lnv_b = (const float*)d_in[5];
  const float* w_out = (const float*)d_in[6];
  const float* b_out = (const float*)d_in[7];
  float* out = (float*)d_out;

  // Workspace layout (~43 MB):
  float* qkv  = (float*)d_ws;                      // 4096*1536 fp32
  float* cbuf = qkv + (size_t)Mm * TQKV;           // 512*4160 fp32
  _Float16* atth = (_Float16*)(cbuf + (size_t)Bb * Hh * NCH * CSZ);
  _Float16* attl = atth + (size_t)Mm * INNER;
  _Float16* woh  = attl + (size_t)Mm * INNER;
  _Float16* wol  = woh + (size_t)INNER * 512;

  // 1. QKV GEMM (fp32 VALU — required accuracy; 128x64 tile, 768 blocks)
  gemm1_f32<<<dim3(TQKV / 64, Mm / 128), 256, 0, stream>>>(x, w_qkv, qkv);

  // 2. Per-head LayerNorm on k, v (in place, fp32)
  ln_kv<<<(2 * Bb * Nn * Hh * 64) / 256, 256, 0, stream>>>(
      qkv, lnk_w, lnk_b, lnv_w, lnv_b);

  // 3. Per-chunk K^T V and colsum(K)
  chunk_sums<<<Bb * Hh * NCH, 256, 0, stream>>>(qkv, cbuf);

  // 4. Exclusive prefix over chunks (parallel over columns)
  chunk_prefix<<<dim3((CSZ + 255) / 256, Bb * Hh), 256, 0, stream>>>(cbuf);

  // 5. Split w_out for GEMM2
  split_f16_k<<<256, 256, 0, stream>>>(w_out, woh, wol, INNER * 512 / 4);

  // 6. Per-chunk attention -> attn split f16
  chunk_attn<<<Bb * Hh * NCH, 256, 0, stream>>>(qkv, cbuf, atth, attl);

  // 7. Output GEMM: out = attn * w_out^T + b_out (R4-exact split MFMA)
  gemm_split_nt<<<dim3(INNER / 64, Mm / 128), 256, 0, stream>>>(
      atth, attl, woh, wol, b_out, out, INNER, 512);
}